// Round 9
// baseline (3396.664 us; speedup 1.0000x reference)
//
#include <hip/hip_runtime.h>
#include <stdint.h>
#include <stddef.h>

typedef __attribute__((ext_vector_type(8))) _Float16 half8;
typedef __attribute__((ext_vector_type(8))) unsigned short ushort8;
typedef __attribute__((ext_vector_type(4))) float f4;

namespace {
constexpr int kSteps = 255;   // reference iterates t = 0 .. T-2
constexpr int KTOT = 1152;    // 1024 (h) + 128 (x)

// workspace layout (bytes); total ~45 MB
// h layout: [group(8)][ub(64)][row(64)][u(16)] fp16 -> block-contiguous 2KB slices
constexpr size_t OFF_H0   = 0;                                   // 1 MB  h ping
constexpr size_t OFF_CNT  = (size_t)1 << 20;                     // 4 KB  barrier counters
constexpr size_t OFF_H1   = ((size_t)1 << 20) + 4096;            // 1 MB  h pong
constexpr size_t OFF_BSUM = OFF_H1 + ((size_t)1 << 20);          // 16 KB b_ih+b_hh (fp32)
constexpr size_t OFF_WCAT = OFF_BSUM + 16384;                    // 9.4 MB fp16 [4096][1152]
constexpr size_t OFF_XT   = OFF_WCAT + (size_t)4096 * KTOT * 2;  // 33.4 MB fp16 [255][512][128]
}

__device__ __forceinline__ unsigned short f2h(float f) {
  _Float16 h = (_Float16)f;
  return __builtin_bit_cast(unsigned short, h);
}
__device__ __forceinline__ float h2f(unsigned short s) {
  return (float)__builtin_bit_cast(_Float16, s);
}

// ---------- prep 1: Wcat fp16 + bsum ----------
__global__ void prep_wcat(const float* __restrict__ Wih, const float* __restrict__ Whh,
                          const float* __restrict__ bih, const float* __restrict__ bhh,
                          char* __restrict__ ws) {
  if (blockIdx.x < 2304) {
    unsigned gid = blockIdx.x * 256 + threadIdx.x;
    unsigned row = gid / 144, cc = gid % 144;
    const float* src = (cc < 128) ? (Whh + (size_t)row * 1024 + (size_t)cc * 8)
                                  : (Wih + (size_t)row * 128 + (size_t)(cc - 128) * 8);
    ushort8 o;
#pragma unroll
    for (int j = 0; j < 8; j++) o[j] = f2h(src[j]);
    *(ushort8*)((unsigned short*)(ws + OFF_WCAT) + (size_t)row * KTOT + cc * 8) = o;
  } else {
    int i = (blockIdx.x - 2304) * 256 + threadIdx.x;
    ((float*)(ws + OFF_BSUM))[i] = bih[i] + bhh[i];
  }
}

// ---------- prep 2: xT[t][b][i] = fp16(x[b][i][t]) ----------
__global__ void prep_xt(const float* __restrict__ x, char* __restrict__ ws) {
  unsigned short* xT = (unsigned short*)(ws + OFF_XT);
  __shared__ unsigned short tile[128][72];
  const int b = blockIdx.x >> 2;
  const int t0 = (blockIdx.x & 3) * 64;
  const int wv = threadIdx.x >> 6, tl = threadIdx.x & 63;
  if (t0 + tl < 255) {
#pragma unroll
    for (int ii = 0; ii < 32; ii++) {
      int i = wv + ii * 4;
      tile[i][tl] = f2h(x[((size_t)b * 128 + i) * 256 + t0 + tl]);
    }
  }
  __syncthreads();
  const int tl2 = threadIdx.x >> 4, ic = threadIdx.x & 15;
#pragma unroll
  for (int pp = 0; pp < 4; pp++) {
    int tloc = pp * 16 + tl2;
    int t = t0 + tloc;
    if (t < 255) {
      ushort8 v;
#pragma unroll
      for (int j = 0; j < 8; j++) v[j] = tile[ic * 8 + j][tloc];
      *(ushort8*)&xT[((size_t)t * 512 + b) * 128 + ic * 8] = v;
    }
  }
}

// counted-vmcnt + barrier (T3/T4)
#define WAITBAR(N) do { \
    asm volatile("s_waitcnt vmcnt(" #N ") lgkmcnt(0)\n\ts_barrier" ::: "memory"); \
    __builtin_amdgcn_sched_barrier(0); \
  } while (0)

// ---------- persistent LSTM kernel ----------
// grid 512 = 8 groups (64 rows) x 64 unit-blocks (16 units). 256 thr = 4 waves = 2K x 2N.
// LDS 64KB -> 2 blocks/CU; co-resident blocks belong to DIFFERENT groups (bid, bid+256)
// -> independent stalls, TLP hides LLC latency / rendezvous / barriers.
// Coherence (r8-proven): h write-through sc0 sc1; relaxed release; early inv; bounded spin.
__global__ __launch_bounds__(256, 2) void lstm_persist(char* __restrict__ ws) {
  const unsigned short* __restrict__ wcat = (const unsigned short*)(ws + OFF_WCAT);
  const float* __restrict__ bsum = (const float*)(ws + OFF_BSUM);
  const unsigned short* __restrict__ xT = (const unsigned short*)(ws + OFF_XT);
  unsigned short* h0 = (unsigned short*)(ws + OFF_H0);
  unsigned short* h1 = (unsigned short*)(ws + OFF_H1);

  __shared__ __align__(16) unsigned short Ab[4][8192];   // 4 x 16KB chunk bufs / reduce scratch

  const int tid = threadIdx.x;
  const int lane = tid & 63;
  const int w = tid >> 6;         // 0..3
  const int wk = w & 1;           // K half (64 cols of each 128-col chunk)
  const int wn = w >> 1;          // N half (32 of 64 gate cols)
  const int l15 = lane & 15, l4 = lane >> 4;
  const int gblk = blockIdx.x >> 6;    // 0..7
  const int cblk = blockIdx.x & 63;
  const int B0 = gblk * 64;
  const int U0 = cblk * 16;
  int* cntp = (int*)(ws + OFF_CNT) + gblk * 16;

  // ---- weight fragments -> registers (col n = wn*32+nf*16+l15 -> unit n>>2, gate n&3) ----
  half8 bf[9][2][2];   // [chunk][ks][nf] = 36 half8 = 144 VGPR (persist whole kernel)
  float bs[2];
#pragma unroll
  for (int nf = 0; nf < 2; nf++) {
    int u = wn * 8 + nf * 4 + (l15 >> 2);
    int R = (l15 & 3) * 1024 + U0 + u;          // PyTorch gate order i,f,g,o
    bs[nf] = bsum[R];
#pragma unroll
    for (int c = 0; c < 9; c++)
#pragma unroll
      for (int ks = 0; ks < 2; ks++)
        bf[c][ks][nf] = *(const half8*)&wcat[(size_t)R * KTOT + c * 128 + wk * 64 + ks * 32 + l4 * 8];
  }
  const float bseed0 = (wk == 0) ? bs[0] : 0.f;   // 2-way K reduce: one half seeds bias
  const float bseed1 = (wk == 0) ? bs[1] : 0.f;

  // ---- staging: chunk 16KB = 16 slots of 1KB; slot s = w*4+i (wave-uniform LDS base) ----
  // LDS (row, c16) holds G(row, c16 ^ (row&7)); source pre-inverse-swizzled (rule #21).
  int hoffc[4], xoff[4];
#pragma unroll
  for (int i = 0; i < 4; i++) {
    int s = w * 4 + i;
    int row = s * 4 + (lane >> 4);            // 0..63
    int cg = (lane & 15) ^ (row & 7);
    hoffc[i] = (cg >> 1) * 1024 + row * 16 + (cg & 1) * 8;   // elems; +c*8192/chunk
    xoff[i] = (B0 + row) * 128 + cg * 8;
  }
  // A ds_read: row = m*16+l15, c16 = (wk*8+ks*4+l4) ^ (row&7)
  int aofs[4][2];
#pragma unroll
  for (int m = 0; m < 4; m++)
#pragma unroll
    for (int ks = 0; ks < 2; ks++)
      aofs[m][ks] = (m * 16 + l15) * 256 + (((wk * 8 + ks * 4 + l4) ^ (l15 & 7)) * 16);

  // reduce-exchange constants (writer): n = wn*32+nf*16+l15, hn = (n^(n>>3))&7
  int nb16[2], hn[2];
#pragma unroll
  for (int nf = 0; nf < 2; nf++) {
    int n = wn * 32 + nf * 16 + l15;
    nb16[nf] = n * 16;
    hn[nf] = (n ^ (n >> 3)) & 7;
  }
  // reader: thread owns (unit u, row-quad rf): 4 cells, all 256 threads active
  const int ucell = tid & 15;
  const int rfr = tid >> 4;    // 0..15
  int ra16[4];
#pragma unroll
  for (int g2 = 0; g2 < 4; g2++) {
    int n = 4 * ucell + g2;
    ra16[g2] = n * 16 + (rfr ^ ((n ^ (n >> 3)) & 7));
  }
  char* lds = (char*)&Ab[0][0];

  f4 acc[4][2];

#define STAGE_H(C, BUF) do { \
    _Pragma("unroll") \
    for (int i = 0; i < 4; i++) \
      __builtin_amdgcn_global_load_lds( \
          (const __attribute__((address_space(1))) void*)(hsrcg + hoffc[i] + (C) * 8192), \
          (__attribute__((address_space(3))) void*)((char*)&Ab[BUF][0] + (w * 4 + i) * 1024), \
          16, 0, 0); \
  } while (0)

#define STAGE_X() do { \
    _Pragma("unroll") \
    for (int i = 0; i < 4; i++) \
      __builtin_amdgcn_global_load_lds( \
          (const __attribute__((address_space(1))) void*)(xslab + xoff[i]), \
          (__attribute__((address_space(3))) void*)((char*)&Ab[3][0] + (w * 4 + i) * 1024), \
          16, 0, 0); \
  } while (0)

#define COMPUTE(C, BUF) do { \
    const char* _b = (const char*)&Ab[BUF][0]; \
    _Pragma("unroll") \
    for (int ks = 0; ks < 2; ks++) { \
      half8 a0 = *(const half8*)(_b + aofs[0][ks]); \
      half8 a1 = *(const half8*)(_b + aofs[1][ks]); \
      half8 a2 = *(const half8*)(_b + aofs[2][ks]); \
      half8 a3 = *(const half8*)(_b + aofs[3][ks]); \
      acc[0][0] = __builtin_amdgcn_mfma_f32_16x16x32_f16(a0, bf[C][ks][0], acc[0][0], 0, 0, 0); \
      acc[0][1] = __builtin_amdgcn_mfma_f32_16x16x32_f16(a0, bf[C][ks][1], acc[0][1], 0, 0, 0); \
      acc[1][0] = __builtin_amdgcn_mfma_f32_16x16x32_f16(a1, bf[C][ks][0], acc[1][0], 0, 0, 0); \
      acc[1][1] = __builtin_amdgcn_mfma_f32_16x16x32_f16(a1, bf[C][ks][1], acc[1][1], 0, 0, 0); \
      acc[2][0] = __builtin_amdgcn_mfma_f32_16x16x32_f16(a2, bf[C][ks][0], acc[2][0], 0, 0, 0); \
      acc[2][1] = __builtin_amdgcn_mfma_f32_16x16x32_f16(a2, bf[C][ks][1], acc[2][1], 0, 0, 0); \
      acc[3][0] = __builtin_amdgcn_mfma_f32_16x16x32_f16(a3, bf[C][ks][0], acc[3][0], 0, 0, 0); \
      acc[3][1] = __builtin_amdgcn_mfma_f32_16x16x32_f16(a3, bf[C][ks][1], acc[3][1], 0, 0, 0); \
    } \
  } while (0)

  f4 creg = {0.f, 0.f, 0.f, 0.f};   // 4 cells (rows rfr*4+j, unit ucell)

#pragma unroll 1
  for (int t = 0; t < kSteps; t++) {
    const unsigned short* hsrcg = ((t & 1) ? h1 : h0) + gblk * 65536;
    unsigned short* hdst = (t & 1) ? h0 : h1;
    const unsigned short* xslab = xT + (size_t)t * (512 * 128);

#pragma unroll
    for (int m = 0; m < 4; m++) {
      acc[m][0] = (f4){bseed0, bseed0, bseed0, bseed0};
      acc[m][1] = (f4){bseed1, bseed1, bseed1, bseed1};
    }

    STAGE_X();                   // flies during the group-barrier wait

    if (tid == 0) {
      // EARLY acquire/inv (no writebacks exist anywhere: h is write-through).
      int f0 = __hip_atomic_load(cntp, __ATOMIC_ACQUIRE, __HIP_MEMORY_SCOPE_AGENT);
      asm volatile("" :: "v"(f0));
      int target = 64 * t;
      int guard = 1 << 18;
      while (guard--) {           // relaxed LLC-bypass polling: no L2 thrash
        int c;
        asm volatile("global_load_dword %0, %1, off sc0 sc1\n\ts_waitcnt vmcnt(0)"
                     : "=v"(c) : "v"(cntp) : "memory");
        if (c >= target) break;
        __builtin_amdgcn_s_sleep(2);
      }
    }
    __syncthreads();             // join; drains x staging (vmcnt 0)

    // r8-proven 2-deep schedule (8 loads in flight; overwrite >= 1 barrier after last read)
    STAGE_H(0, 0); STAGE_H(1, 1);
    COMPUTE(8, 3);                    // x contribution (buf3 resident)
    STAGE_H(2, 2);
    WAITBAR(8);  COMPUTE(0, 0);
    STAGE_H(3, 3);
    WAITBAR(8);  COMPUTE(1, 1);
    STAGE_H(4, 0);
    WAITBAR(8);  COMPUTE(2, 2);
    STAGE_H(5, 1);
    WAITBAR(8);  COMPUTE(3, 3);
    STAGE_H(6, 2);
    WAITBAR(8);  COMPUTE(4, 0);
    STAGE_H(7, 3);
    WAITBAR(8);  COMPUTE(5, 1);
    WAITBAR(4);  COMPUTE(6, 2);
    WAITBAR(0);  COMPUTE(7, 3);

    // ---- 2-way K reduction through LDS (32KB in bufs 0,1) ----
    asm volatile("s_waitcnt lgkmcnt(0)\n\ts_barrier" ::: "memory");  // all staging reads done
#pragma unroll
    for (int m = 0; m < 4; m++)
#pragma unroll
      for (int nf = 0; nf < 2; nf++) {
        int rf = m * 4 + l4;
        *(f4*)(lds + (size_t)(wk * 1024 + nb16[nf] + (rf ^ hn[nf])) * 16) = acc[m][nf];
      }
    __syncthreads();
    {
      f4 gs[4];
#pragma unroll
      for (int g2 = 0; g2 < 4; g2++) {
        f4 v0 = *(const f4*)(lds + (size_t)ra16[g2] * 16);
        f4 v1 = *(const f4*)(lds + 16384 + (size_t)ra16[g2] * 16);
        gs[g2] = v0 + v1;
      }
      size_t hb = (size_t)((gblk * 64 + cblk) * 64 + rfr * 4) * 16 + ucell;
#pragma unroll
      for (int j = 0; j < 4; j++) {
        float ig = 1.f / (1.f + __expf(-gs[0][j]));
        float fg = 1.f / (1.f + __expf(-gs[1][j]));
        float gg = 2.f / (1.f + __expf(-2.f * gs[2][j])) - 1.f;
        float og = 1.f / (1.f + __expf(-gs[3][j]));
        float cn = fg * creg[j] + ig * gg;
        creg[j] = cn;
        float th = 2.f / (1.f + __expf(-2.f * cn)) - 1.f;
        // write-through to LLC: coherent across XCDs, leaves no dirty L2 line
        unsigned short* hp = hdst + hb + (size_t)j * 16;
        unsigned hv = f2h(og * th);
        asm volatile("global_store_short %0, %1, off sc0 sc1"
                     :: "v"(hp), "v"(hv) : "memory");
      }
    }
    __syncthreads();             // drains h stores (ack'd at LLC) + reduce reads
    if (tid == 0)                // RELAXED: no buffer_wbl2 (nothing dirty to flush)
      __hip_atomic_fetch_add(cntp, 1, __ATOMIC_RELAXED, __HIP_MEMORY_SCOPE_AGENT);
  }
#undef STAGE_H
#undef STAGE_X
#undef COMPUTE
}

// ---------- FC: out = h_last @ W_fc^T + b_fc ----------
__global__ void fc_kernel(const char* __restrict__ ws, const float* __restrict__ Wfc,
                          const float* __restrict__ bfc, float* __restrict__ out) {
  const unsigned short* h = (const unsigned short*)(ws + OFF_H1);  // t=254 writes h1
  int o = threadIdx.x & 127;
  int b = blockIdx.x * 2 + (threadIdx.x >> 7);
  const float* wrow = Wfc + (size_t)o * 1024;
  float acc = bfc[o];
  int gb = b >> 6, rb = b & 63;
#pragma unroll 4
  for (int k = 0; k < 1024; k += 8) {
    ushort8 hv = *(const ushort8*)&h[((size_t)(gb * 64 + (k >> 4)) * 64 + rb) * 16 + (k & 15)];
    f4 w0 = *(const f4*)&wrow[k];
    f4 w1 = *(const f4*)&wrow[k + 4];
#pragma unroll
    for (int j = 0; j < 4; j++) acc += h2f(hv[j]) * w0[j];
#pragma unroll
    for (int j = 0; j < 4; j++) acc += h2f(hv[4 + j]) * w1[j];
  }
  out[(size_t)b * 128 + o] = acc;
}

extern "C" void kernel_launch(void* const* d_in, const int* in_sizes, int n_in,
                              void* d_out, int out_size, void* d_ws, size_t ws_size,
                              hipStream_t stream) {
  const float* x   = (const float*)d_in[0];
  const float* Wih = (const float*)d_in[1];
  const float* Whh = (const float*)d_in[2];
  const float* bih = (const float*)d_in[3];
  const float* bhh = (const float*)d_in[4];
  const float* Wfc = (const float*)d_in[5];
  const float* bfc = (const float*)d_in[6];
  char* ws = (char*)d_ws;

  hipMemsetAsync(ws + OFF_H0, 0, ((size_t)1 << 20) + 4096, stream);
  prep_wcat<<<2320, 256, 0, stream>>>(Wih, Whh, bih, bhh, ws);
  prep_xt<<<2048, 256, 0, stream>>>(x, ws);
  lstm_persist<<<512, 256, 0, stream>>>(ws);
  fc_kernel<<<256, 256, 0, stream>>>(ws, Wfc, bfc, (float*)d_out);
}

// Round 10
// 2418.189 us; speedup vs baseline: 1.4046x; 1.4046x over previous
//
#include <hip/hip_runtime.h>
#include <stdint.h>
#include <stddef.h>

typedef __attribute__((ext_vector_type(8))) _Float16 half8;
typedef __attribute__((ext_vector_type(8))) unsigned short ushort8;
typedef __attribute__((ext_vector_type(4))) float f4;

namespace {
constexpr int kSteps = 255;   // reference iterates t = 0 .. T-2
constexpr int KTOT = 1152;    // 1024 (h) + 128 (x)

// workspace layout (bytes); total ~45 MB
// h layout: [group(4)][ub(64)][row(128)][u(16)] fp16 -> block-contiguous 4KB slices
constexpr size_t OFF_H0   = 0;                                   // 1 MB  h ping
constexpr size_t OFF_CNT  = (size_t)1 << 20;                     // 4 KB  barrier counters
constexpr size_t OFF_H1   = ((size_t)1 << 20) + 4096;            // 1 MB  h pong
constexpr size_t OFF_BSUM = OFF_H1 + ((size_t)1 << 20);          // 16 KB b_ih+b_hh (fp32)
constexpr size_t OFF_WCAT = OFF_BSUM + 16384;                    // 9.4 MB fp16 [4096][1152]
constexpr size_t OFF_XT   = OFF_WCAT + (size_t)4096 * KTOT * 2;  // 33.4 MB fp16 [255][512][128]
}

__device__ __forceinline__ unsigned short f2h(float f) {
  _Float16 h = (_Float16)f;
  return __builtin_bit_cast(unsigned short, h);
}
__device__ __forceinline__ float h2f(unsigned short s) {
  return (float)__builtin_bit_cast(_Float16, s);
}

// ---------- prep 1: Wcat fp16 + bsum ----------
__global__ void prep_wcat(const float* __restrict__ Wih, const float* __restrict__ Whh,
                          const float* __restrict__ bih, const float* __restrict__ bhh,
                          char* __restrict__ ws) {
  if (blockIdx.x < 2304) {
    unsigned gid = blockIdx.x * 256 + threadIdx.x;
    unsigned row = gid / 144, cc = gid % 144;
    const float* src = (cc < 128) ? (Whh + (size_t)row * 1024 + (size_t)cc * 8)
                                  : (Wih + (size_t)row * 128 + (size_t)(cc - 128) * 8);
    ushort8 o;
#pragma unroll
    for (int j = 0; j < 8; j++) o[j] = f2h(src[j]);
    *(ushort8*)((unsigned short*)(ws + OFF_WCAT) + (size_t)row * KTOT + cc * 8) = o;
  } else {
    int i = (blockIdx.x - 2304) * 256 + threadIdx.x;
    ((float*)(ws + OFF_BSUM))[i] = bih[i] + bhh[i];
  }
}

// ---------- prep 2: xT[t][b][i] = fp16(x[b][i][t]) ----------
__global__ void prep_xt(const float* __restrict__ x, char* __restrict__ ws) {
  unsigned short* xT = (unsigned short*)(ws + OFF_XT);
  __shared__ unsigned short tile[128][72];
  const int b = blockIdx.x >> 2;
  const int t0 = (blockIdx.x & 3) * 64;
  const int wv = threadIdx.x >> 6, tl = threadIdx.x & 63;
  if (t0 + tl < 255) {
#pragma unroll
    for (int ii = 0; ii < 32; ii++) {
      int i = wv + ii * 4;
      tile[i][tl] = f2h(x[((size_t)b * 128 + i) * 256 + t0 + tl]);
    }
  }
  __syncthreads();
  const int tl2 = threadIdx.x >> 4, ic = threadIdx.x & 15;
#pragma unroll
  for (int pp = 0; pp < 4; pp++) {
    int tloc = pp * 16 + tl2;
    int t = t0 + tloc;
    if (t < 255) {
      ushort8 v;
#pragma unroll
      for (int j = 0; j < 8; j++) v[j] = tile[ic * 8 + j][tloc];
      *(ushort8*)&xT[((size_t)t * 512 + b) * 128 + ic * 8] = v;
    }
  }
}

// counted-vmcnt + barrier (T3/T4)
#define WAITBAR(N) do { \
    asm volatile("s_waitcnt vmcnt(" #N ") lgkmcnt(0)\n\ts_barrier" ::: "memory"); \
    __builtin_amdgcn_sched_barrier(0); \
  } while (0)

// ---------- persistent LSTM kernel (r8 skeleton) ----------
// grid 256 = 4 groups (128 rows) x 64 unit-blocks (16 units). 8 waves = 4K x 2N.
// Coherence v2: h stores write-through (sc0 sc1) -> LLC; h staging LOADS are
// LLC-direct (aux=SC0|SC1=17) -> always fresh, NO L2 invalidate anywhere.
// xT/wcat stay L2-resident (no inv storms). Release = relaxed (nothing dirty).
__global__ __launch_bounds__(512, 1) void lstm_persist(char* __restrict__ ws) {
  const unsigned short* __restrict__ wcat = (const unsigned short*)(ws + OFF_WCAT);
  const float* __restrict__ bsum = (const float*)(ws + OFF_BSUM);
  const unsigned short* __restrict__ xT = (const unsigned short*)(ws + OFF_XT);
  unsigned short* h0 = (unsigned short*)(ws + OFF_H0);
  unsigned short* h1 = (unsigned short*)(ws + OFF_H1);

  __shared__ __align__(16) unsigned short Ab[4][16384];   // 4 x 32KB chunk bufs / reduce scratch

  const int tid = threadIdx.x;
  const int lane = tid & 63;
  const int w = tid >> 6;
  const int wk = w & 3;           // K group (k-slice parity mod 4)
  const int wn = w >> 2;          // N half
  const int l15 = lane & 15, l4 = lane >> 4;
  const int gblk = blockIdx.x >> 6;
  const int cblk = blockIdx.x & 63;
  const int B0 = gblk * 128;
  const int U0 = cblk * 16;
  int* cntp = (int*)(ws + OFF_CNT) + gblk * 16;

  // ---- weight fragments -> registers (col n = wn*32+nf*16+l15 -> unit n>>2, gate n&3) ----
  half8 bf[9][2];
  float bs[2];
#pragma unroll
  for (int nf = 0; nf < 2; nf++) {
    int u = wn * 8 + nf * 4 + (l15 >> 2);
    int R = (l15 & 3) * 1024 + U0 + u;          // PyTorch gate order i,f,g,o
    bs[nf] = bsum[R];
#pragma unroll
    for (int c = 0; c < 9; c++)
      bf[c][nf] = *(const half8*)&wcat[(size_t)R * KTOT + c * 128 + wk * 32 + l4 * 8];
  }
  const float bseed0 = (wk == 0) ? bs[0] : 0.f;
  const float bseed1 = (wk == 0) ? bs[1] : 0.f;

  // ---- staging: 32 slots of 1KB per 32KB chunk; slot s = w*4+i (wave-uniform LDS base) ----
  // LDS (row, c16) holds G(row, c16 ^ (row&7)); source pre-inverse-swizzled (rule #21).
  int hoffc[4], xoff[4];
#pragma unroll
  for (int i = 0; i < 4; i++) {
    int s = w * 4 + i;
    int row = s * 4 + (lane >> 4);
    int cg = (lane & 15) ^ (row & 7);
    hoffc[i] = (cg >> 1) * 2048 + row * 16 + (cg & 1) * 8;   // + c*16384 per chunk
    xoff[i] = (B0 + row) * 128 + cg * 8;
  }
  // A ds_read: row = m*16+l15, c16 = (wk*4+l4) ^ (l15&7)
  const int aBase = l15 * 256 + (((wk * 4 + l4) ^ (l15 & 7)) * 16);

  // reduce-exchange swizzle constants (writer side)
  int nb16[2], hn[2];
#pragma unroll
  for (int nf = 0; nf < 2; nf++) {
    int n = wn * 32 + nf * 16 + l15;
    nb16[nf] = n * 32;
    hn[nf] = (n ^ (n >> 3)) & 7;
  }
  // reader side: thread owns cells (rows 4*rfr..4*rfr+3, unit ucell)
  const int ucell = tid & 15;
  const int rfr = tid >> 4;
  int ra16[4];
#pragma unroll
  for (int g2 = 0; g2 < 4; g2++) {
    int n = 4 * ucell + g2;
    ra16[g2] = n * 32 + (rfr ^ ((n ^ (n >> 3)) & 7));
  }
  char* lds = (char*)&Ab[0][0];

  f4 acc[8][2];

// h loads: aux=17 (SC0|SC1) -> LLC-direct, always-fresh, no inv needed
#define STAGE_H(C, BUF) do { \
    _Pragma("unroll") \
    for (int i = 0; i < 4; i++) \
      __builtin_amdgcn_global_load_lds( \
          (const __attribute__((address_space(1))) void*)(hsrcg + hoffc[i] + (C) * 16384), \
          (__attribute__((address_space(3))) void*)((char*)&Ab[BUF][0] + (w * 4 + i) * 1024), \
          16, 0, 17); \
  } while (0)

// x loads: normal caching (xT immutable during kernel -> L2-hot, no staleness)
#define STAGE_X() do { \
    _Pragma("unroll") \
    for (int i = 0; i < 4; i++) \
      __builtin_amdgcn_global_load_lds( \
          (const __attribute__((address_space(1))) void*)(xslab + xoff[i]), \
          (__attribute__((address_space(3))) void*)((char*)&Ab[3][0] + (w * 4 + i) * 1024), \
          16, 0, 0); \
  } while (0)

#define COMPUTE(C, BUF) do { \
    const char* _b = (const char*)&Ab[BUF][0] + aBase; \
    half8 a0 = *(const half8*)(_b); \
    half8 a1 = *(const half8*)(_b + 4096); \
    half8 a2 = *(const half8*)(_b + 8192); \
    half8 a3 = *(const half8*)(_b + 12288); \
    half8 a4 = *(const half8*)(_b + 16384); \
    half8 a5 = *(const half8*)(_b + 20480); \
    half8 a6 = *(const half8*)(_b + 24576); \
    half8 a7 = *(const half8*)(_b + 28672); \
    acc[0][0] = __builtin_amdgcn_mfma_f32_16x16x32_f16(a0, bf[C][0], acc[0][0], 0, 0, 0); \
    acc[0][1] = __builtin_amdgcn_mfma_f32_16x16x32_f16(a0, bf[C][1], acc[0][1], 0, 0, 0); \
    acc[1][0] = __builtin_amdgcn_mfma_f32_16x16x32_f16(a1, bf[C][0], acc[1][0], 0, 0, 0); \
    acc[1][1] = __builtin_amdgcn_mfma_f32_16x16x32_f16(a1, bf[C][1], acc[1][1], 0, 0, 0); \
    acc[2][0] = __builtin_amdgcn_mfma_f32_16x16x32_f16(a2, bf[C][0], acc[2][0], 0, 0, 0); \
    acc[2][1] = __builtin_amdgcn_mfma_f32_16x16x32_f16(a2, bf[C][1], acc[2][1], 0, 0, 0); \
    acc[3][0] = __builtin_amdgcn_mfma_f32_16x16x32_f16(a3, bf[C][0], acc[3][0], 0, 0, 0); \
    acc[3][1] = __builtin_amdgcn_mfma_f32_16x16x32_f16(a3, bf[C][1], acc[3][1], 0, 0, 0); \
    acc[4][0] = __builtin_amdgcn_mfma_f32_16x16x32_f16(a4, bf[C][0], acc[4][0], 0, 0, 0); \
    acc[4][1] = __builtin_amdgcn_mfma_f32_16x16x32_f16(a4, bf[C][1], acc[4][1], 0, 0, 0); \
    acc[5][0] = __builtin_amdgcn_mfma_f32_16x16x32_f16(a5, bf[C][0], acc[5][0], 0, 0, 0); \
    acc[5][1] = __builtin_amdgcn_mfma_f32_16x16x32_f16(a5, bf[C][1], acc[5][1], 0, 0, 0); \
    acc[6][0] = __builtin_amdgcn_mfma_f32_16x16x32_f16(a6, bf[C][0], acc[6][0], 0, 0, 0); \
    acc[6][1] = __builtin_amdgcn_mfma_f32_16x16x32_f16(a6, bf[C][1], acc[6][1], 0, 0, 0); \
    acc[7][0] = __builtin_amdgcn_mfma_f32_16x16x32_f16(a7, bf[C][0], acc[7][0], 0, 0, 0); \
    acc[7][1] = __builtin_amdgcn_mfma_f32_16x16x32_f16(a7, bf[C][1], acc[7][1], 0, 0, 0); \
  } while (0)

  f4 creg = {0.f, 0.f, 0.f, 0.f};   // 4 cells (rows 4*rfr+j, unit ucell)

#pragma unroll 1
  for (int t = 0; t < kSteps; t++) {
    const unsigned short* hsrcg = ((t & 1) ? h1 : h0) + gblk * 131072;
    unsigned short* hdst = (t & 1) ? h0 : h1;
    const unsigned short* xslab = xT + (size_t)t * (512 * 128);

#pragma unroll
    for (int m = 0; m < 8; m++) {
      acc[m][0] = (f4){bseed0, bseed0, bseed0, bseed0};
      acc[m][1] = (f4){bseed1, bseed1, bseed1, bseed1};
    }

    STAGE_X();                   // flies during the group-barrier wait

    if (tid == 0) {              // all 64 blocks of this group finished step t-1?
      int target = 64 * t;       // LLC-bypass polling; NO acquire/inv anywhere
      int guard = 1 << 18;
      while (guard--) {
        int c;
        asm volatile("global_load_dword %0, %1, off sc0 sc1\n\ts_waitcnt vmcnt(0)"
                     : "=v"(c) : "v"(cntp) : "memory");
        if (c >= target) break;
        __builtin_amdgcn_s_sleep(2);
      }
    }
    __syncthreads();             // join; drains x staging (vmcnt 0)

    // r8-proven 2-deep schedule (8 loads in flight; overwrite >= 1 barrier after last read)
    STAGE_H(0, 0); STAGE_H(1, 1);
    COMPUTE(8, 3);                    // x contribution (buf3 resident)
    STAGE_H(2, 2);
    WAITBAR(8);  COMPUTE(0, 0);
    STAGE_H(3, 3);
    WAITBAR(8);  COMPUTE(1, 1);
    STAGE_H(4, 0);
    WAITBAR(8);  COMPUTE(2, 2);
    STAGE_H(5, 1);
    WAITBAR(8);  COMPUTE(3, 3);
    STAGE_H(6, 2);
    WAITBAR(8);  COMPUTE(4, 0);
    STAGE_H(7, 3);
    WAITBAR(8);  COMPUTE(5, 1);
    WAITBAR(4);  COMPUTE(6, 2);
    WAITBAR(0);  COMPUTE(7, 3);

    // ---- 4-way K reduction through LDS (128KB over bufs 0-3) ----
    asm volatile("s_waitcnt lgkmcnt(0)\n\ts_barrier" ::: "memory");  // staging reads done
#pragma unroll
    for (int m = 0; m < 8; m++)
#pragma unroll
      for (int nf = 0; nf < 2; nf++) {
        int rf = m * 4 + l4;
        *(f4*)(lds + (size_t)(wk * 2048 + nb16[nf] + (rf ^ hn[nf])) * 16) = acc[m][nf];
      }
    __syncthreads();
    {
      f4 gs[4];
#pragma unroll
      for (int g2 = 0; g2 < 4; g2++) {
        f4 v0 = *(const f4*)(lds + (size_t)ra16[g2] * 16);
        f4 v1 = *(const f4*)(lds + 32768 + (size_t)ra16[g2] * 16);
        f4 v2 = *(const f4*)(lds + 65536 + (size_t)ra16[g2] * 16);
        f4 v3 = *(const f4*)(lds + 98304 + (size_t)ra16[g2] * 16);
        gs[g2] = (v0 + v1) + (v2 + v3);
      }
      size_t hb = (size_t)((gblk * 64 + cblk) * 128 + rfr * 4) * 16 + ucell;
#pragma unroll
      for (int j = 0; j < 4; j++) {
        float ig = 1.f / (1.f + __expf(-gs[0][j]));
        float fg = 1.f / (1.f + __expf(-gs[1][j]));
        float gg = 2.f / (1.f + __expf(-2.f * gs[2][j])) - 1.f;
        float og = 1.f / (1.f + __expf(-gs[3][j]));
        float cn = fg * creg[j] + ig * gg;
        creg[j] = cn;
        float th = 2.f / (1.f + __expf(-2.f * cn)) - 1.f;
        // write-through to LLC: coherent across XCDs, leaves no dirty L2 line
        unsigned short* hp = hdst + hb + (size_t)j * 16;
        unsigned hv = f2h(og * th);
        asm volatile("global_store_short %0, %1, off sc0 sc1"
                     :: "v"(hp), "v"(hv) : "memory");
      }
    }
    __syncthreads();             // drains h stores (ack'd at LLC) + reduce reads
    if (tid == 0)                // RELAXED: no buffer_wbl2 (nothing dirty to flush)
      __hip_atomic_fetch_add(cntp, 1, __ATOMIC_RELAXED, __HIP_MEMORY_SCOPE_AGENT);
  }
#undef STAGE_H
#undef STAGE_X
#undef COMPUTE
}

// ---------- FC: out = h_last @ W_fc^T + b_fc ----------
__global__ void fc_kernel(const char* __restrict__ ws, const float* __restrict__ Wfc,
                          const float* __restrict__ bfc, float* __restrict__ out) {
  const unsigned short* h = (const unsigned short*)(ws + OFF_H1);  // t=254 writes h1
  int o = threadIdx.x & 127;
  int b = blockIdx.x * 2 + (threadIdx.x >> 7);
  const float* wrow = Wfc + (size_t)o * 1024;
  float acc = bfc[o];
  int gb = b >> 7, rb = b & 127;
#pragma unroll 4
  for (int k = 0; k < 1024; k += 8) {
    ushort8 hv = *(const ushort8*)&h[((size_t)(gb * 64 + (k >> 4)) * 128 + rb) * 16 + (k & 15)];
    f4 w0 = *(const f4*)&wrow[k];
    f4 w1 = *(const f4*)&wrow[k + 4];
#pragma unroll
    for (int j = 0; j < 4; j++) acc += h2f(hv[j]) * w0[j];
#pragma unroll
    for (int j = 0; j < 4; j++) acc += h2f(hv[4 + j]) * w1[j];
  }
  out[(size_t)b * 128 + o] = acc;
}

extern "C" void kernel_launch(void* const* d_in, const int* in_sizes, int n_in,
                              void* d_out, int out_size, void* d_ws, size_t ws_size,
                              hipStream_t stream) {
  const float* x   = (const float*)d_in[0];
  const float* Wih = (const float*)d_in[1];
  const float* Whh = (const float*)d_in[2];
  const float* bih = (const float*)d_in[3];
  const float* bhh = (const float*)d_in[4];
  const float* Wfc = (const float*)d_in[5];
  const float* bfc = (const float*)d_in[6];
  char* ws = (char*)d_ws;

  hipMemsetAsync(ws + OFF_H0, 0, ((size_t)1 << 20) + 4096, stream);
  prep_wcat<<<2320, 256, 0, stream>>>(Wih, Whh, bih, bhh, ws);
  prep_xt<<<2048, 256, 0, stream>>>(x, ws);
  lstm_persist<<<256, 512, 0, stream>>>(ws);
  fc_kernel<<<256, 256, 0, stream>>>(ws, Wfc, bfc, (float*)d_out);
}